// Round 1
// baseline (242.768 us; speedup 1.0000x reference)
//
#include <hip/hip_runtime.h>
#include <hip/hip_bf16.h>
#include <stdint.h>

// GroupTorchGRU: B=1024, U=8, I=H=512, fp32 in/out.
// out[b,u,h] = (1-z)*n + z*h_prev
//   r = sigmoid(xr+hr), z = sigmoid(xz+hz), n = tanh(xn + r*hn)
//   gx = X_u @ W_ih_u^T + b_ih ; gh = H_u @ W_hh_u^T + b_hh
// Strategy: fused bf16-MFMA kernel. Block tile 64(batch) x 64(h), 6 gate
// accumulator tiles, K-loop BK=32 with LDS staging (fp32->bf16 convert).

#define B_ 1024
#define U_ 8
#define I_ 512
#define H_ 512
#define KDIM 512
#define BM 64
#define BN 64
#define BK 32
#define LSTR 40   // LDS row stride in bf16 elems (32 + 8 pad; 80B rows, 16B-aligned)

typedef __attribute__((ext_vector_type(8))) short short8;   // 8 bf16 (4 VGPRs)
typedef __attribute__((ext_vector_type(4))) float floatx4;  // MFMA C/D

__device__ __forceinline__ short f2bf(float f) {
    uint32_t u = __float_as_uint(f);
    uint32_t r = (u + 0x7fffu + ((u >> 16) & 1u)) >> 16;  // RNE
    return (short)r;
}

__global__ __launch_bounds__(256, 2)
void gru_fused_kernel(const float* __restrict__ inputs,   // (B,U,I)
                      const float* __restrict__ hidden,   // (B,U,H)
                      const float* __restrict__ W_ih,     // (U,3H,I)
                      const float* __restrict__ W_hh,     // (U,3H,H)
                      const float* __restrict__ b_ih,     // (U,3H)
                      const float* __restrict__ b_hh,     // (U,3H)
                      float* __restrict__ out)            // (B,U,H)
{
    const int nb = blockIdx.x;   // h tile: 0..7
    const int mb = blockIdx.y;   // batch tile: 0..15
    const int u  = blockIdx.z;   // unit: 0..7
    const int b0 = mb * BM;
    const int h0 = nb * BN;

    const int tid  = threadIdx.x;
    const int lane = tid & 63;
    const int wave = tid >> 6;
    const int lr   = lane & 15;
    const int q    = lane >> 4;
    const int wm   = wave & 1;    // wave row (batch dir), 2x2 wave grid
    const int wn   = wave >> 1;   // wave col (h dir)

    // 8 slabs: 0=X, 1=Hprev(K-cols), 2..4 = W_ih r/z/n, 5..7 = W_hh r/z/n
    __shared__ __align__(16) short lds[8][BM * LSTR];  // 8 * 5120B = 40KB

    // Per-slab global base pointer (row 0, k 0) and row stride (floats)
    const float* srcs[8];
    int rstr[8];
    srcs[0] = inputs + ((size_t)b0 * U_ + u) * I_;           rstr[0] = U_ * I_;
    srcs[1] = hidden + ((size_t)b0 * U_ + u) * H_;           rstr[1] = U_ * H_;
    srcs[2] = W_ih + ((size_t)(u * 3 + 0) * H_ + h0) * I_;   rstr[2] = I_;
    srcs[3] = W_ih + ((size_t)(u * 3 + 1) * H_ + h0) * I_;   rstr[3] = I_;
    srcs[4] = W_ih + ((size_t)(u * 3 + 2) * H_ + h0) * I_;   rstr[4] = I_;
    srcs[5] = W_hh + ((size_t)(u * 3 + 0) * H_ + h0) * H_;   rstr[5] = H_;
    srcs[6] = W_hh + ((size_t)(u * 3 + 1) * H_ + h0) * H_;   rstr[6] = H_;
    srcs[7] = W_hh + ((size_t)(u * 3 + 2) * H_ + h0) * H_;   rstr[7] = H_;

    // Staging assignment: thread t covers row = t/4, 8-float chunk c8 = t%4
    const int srow = tid >> 2;
    const int c8   = (tid & 3) * 8;

    floatx4 acc[6][2][2];
    #pragma unroll
    for (int g = 0; g < 6; ++g)
        #pragma unroll
        for (int mt = 0; mt < 2; ++mt)
            #pragma unroll
            for (int nt = 0; nt < 2; ++nt)
                acc[g][mt][nt] = (floatx4){0.f, 0.f, 0.f, 0.f};

    for (int k0 = 0; k0 < KDIM; k0 += BK) {
        // ---- stage 8 slabs: global fp32 -> bf16 LDS ----
        #pragma unroll
        for (int s = 0; s < 8; ++s) {
            const float* p = srcs[s] + (size_t)srow * rstr[s] + k0 + c8;
            const float4 v0 = ((const float4*)p)[0];
            const float4 v1 = ((const float4*)p)[1];
            short8 w;
            w[0] = f2bf(v0.x); w[1] = f2bf(v0.y); w[2] = f2bf(v0.z); w[3] = f2bf(v0.w);
            w[4] = f2bf(v1.x); w[5] = f2bf(v1.y); w[6] = f2bf(v1.z); w[7] = f2bf(v1.w);
            *(short8*)&lds[s][srow * LSTR + c8] = w;
        }
        __syncthreads();

        // ---- MFMA: 6 gate slabs x 2x2 16-tiles per wave ----
        short8 a_x[2], a_h[2];
        #pragma unroll
        for (int mt = 0; mt < 2; ++mt) {
            a_x[mt] = *(const short8*)&lds[0][(wm * 32 + mt * 16 + lr) * LSTR + q * 8];
            a_h[mt] = *(const short8*)&lds[1][(wm * 32 + mt * 16 + lr) * LSTR + q * 8];
        }
        #pragma unroll
        for (int g = 0; g < 6; ++g) {
            const short8 bf0 = *(const short8*)&lds[2 + g][(wn * 32 + lr) * LSTR + q * 8];
            const short8 bf1 = *(const short8*)&lds[2 + g][(wn * 32 + 16 + lr) * LSTR + q * 8];
            #pragma unroll
            for (int mt = 0; mt < 2; ++mt) {
                const short8 a = (g < 3) ? a_x[mt] : a_h[mt];
                acc[g][mt][0] = __builtin_amdgcn_mfma_f32_16x16x32_bf16(a, bf0, acc[g][mt][0], 0, 0, 0);
                acc[g][mt][1] = __builtin_amdgcn_mfma_f32_16x16x32_bf16(a, bf1, acc[g][mt][1], 0, 0, 0);
            }
        }
        __syncthreads();
    }

    // ---- epilogue: gates in fp32, direct store ----
    const float* bih = b_ih + u * (3 * H_);
    const float* bhh = b_hh + u * (3 * H_);
    #pragma unroll
    for (int nt = 0; nt < 2; ++nt) {
        const int hcol = h0 + wn * 32 + nt * 16 + lr;
        const float bir = bih[hcol],          bhr = bhh[hcol];
        const float biz = bih[H_ + hcol],     bhz = bhh[H_ + hcol];
        const float bin_ = bih[2 * H_ + hcol], bhn = bhh[2 * H_ + hcol];
        #pragma unroll
        for (int mt = 0; mt < 2; ++mt) {
            #pragma unroll
            for (int r = 0; r < 4; ++r) {
                const int brow = b0 + wm * 32 + mt * 16 + q * 4 + r;
                const size_t gidx = ((size_t)brow * U_ + u) * H_ + hcol;
                const float hprev = hidden[gidx];
                const float xr = acc[0][mt][nt][r] + bir;
                const float xz = acc[1][mt][nt][r] + biz;
                const float xn = acc[2][mt][nt][r] + bin_;
                const float hr = acc[3][mt][nt][r] + bhr;
                const float hz = acc[4][mt][nt][r] + bhz;
                const float hn = acc[5][mt][nt][r] + bhn;
                const float rg = 1.f / (1.f + __expf(-(xr + hr)));
                const float zg = 1.f / (1.f + __expf(-(xz + hz)));
                const float ng = tanhf(xn + rg * hn);
                out[gidx] = (1.f - zg) * ng + zg * hprev;
            }
        }
    }
}

extern "C" void kernel_launch(void* const* d_in, const int* in_sizes, int n_in,
                              void* d_out, int out_size, void* d_ws, size_t ws_size,
                              hipStream_t stream) {
    const float* inputs = (const float*)d_in[0];
    const float* hidden = (const float*)d_in[1];
    const float* W_ih   = (const float*)d_in[2];
    const float* W_hh   = (const float*)d_in[3];
    const float* b_ih   = (const float*)d_in[4];
    const float* b_hh   = (const float*)d_in[5];
    float* out = (float*)d_out;

    dim3 grid(H_ / BN, B_ / BM, U_);  // (8, 16, 8) = 1024 blocks
    dim3 block(256);
    gru_fused_kernel<<<grid, block, 0, stream>>>(inputs, hidden, W_ih, W_hh,
                                                 b_ih, b_hh, out);
}

// Round 3
// 194.890 us; speedup vs baseline: 1.2457x; 1.2457x over previous
//
#include <hip/hip_runtime.h>
#include <hip/hip_bf16.h>
#include <stdint.h>

// GroupTorchGRU: B=1024, U=8, I=H=512, fp32 in/out.
// R3: R2 design (512-thread blocks, gate-split waves, register-prefetch
// pipeline, packed fp32->bf16 converts) with union type-pun fix for the
// __builtin_bit_cast compile error.

#define B_ 1024
#define U_ 8
#define I_ 512
#define H_ 512
#define KDIM 512
#define BM 64
#define BN 64
#define BK 32
#define LSTR 40   // bf16 LDS row stride (32 + 8 pad; 80B rows, 16B aligned)
#define ESTR 68   // fp32 epilogue row stride (64 + 4 pad)

typedef __attribute__((ext_vector_type(8))) short short8;   // 8 bf16 (4 VGPRs)
typedef __attribute__((ext_vector_type(4))) float floatx4;  // MFMA C/D

union SmemU {
    short bf[8][BM * LSTR];   // 8 slabs * 5120B = 40960B (K-loop staging)
    float ep[3][BM * ESTR];   // 3 * 17408B = 52224B (gh->gx exchange)
};

__device__ __forceinline__ unsigned int pk2bf(float a, float b) {
    float2 f2; f2.x = a; f2.y = b;
    union { __hip_bfloat162 h; unsigned int u; } cv;
    cv.h = __float22bfloat162_rn(f2);  // v_cvt_pk_bf16_f32
    return cv.u;
}

__global__ __launch_bounds__(512, 4)
void gru_fused_kernel(const float* __restrict__ inputs,   // (B,U,I)
                      const float* __restrict__ hidden,   // (B,U,H)
                      const float* __restrict__ W_ih,     // (U,3H,I)
                      const float* __restrict__ W_hh,     // (U,3H,H)
                      const float* __restrict__ b_ih,     // (U,3H)
                      const float* __restrict__ b_hh,     // (U,3H)
                      float* __restrict__ out)            // (B,U,H)
{
    const int nb = blockIdx.x;   // h tile: 0..7
    const int mb = blockIdx.y;   // batch tile: 0..15
    const int u  = blockIdx.z;   // unit: 0..7
    const int b0 = mb * BM;
    const int h0 = nb * BN;

    const int tid  = threadIdx.x;
    const int lane = tid & 63;
    const int wave = tid >> 6;       // 0..7
    const int lr   = lane & 15;
    const int q    = lane >> 4;
    const int wm   = wave & 1;        // batch-dir wave coord
    const int wn   = (wave >> 1) & 1; // h-dir wave coord
    const int g2   = wave >> 2;       // 0: gx waves, 1: gh waves

    __shared__ SmemU smem;

    // 8 slabs: 0=X, 1=Hprev, 2..4 = W_ih r/z/n, 5..7 = W_hh r/z/n
    const float* srcs[8];
    int rstr[8];
    srcs[0] = inputs + ((size_t)b0 * U_ + u) * I_;           rstr[0] = U_ * I_;
    srcs[1] = hidden + ((size_t)b0 * U_ + u) * H_;           rstr[1] = U_ * H_;
    srcs[2] = W_ih + ((size_t)(u * 3 + 0) * H_ + h0) * I_;   rstr[2] = I_;
    srcs[3] = W_ih + ((size_t)(u * 3 + 1) * H_ + h0) * I_;   rstr[3] = I_;
    srcs[4] = W_ih + ((size_t)(u * 3 + 2) * H_ + h0) * I_;   rstr[4] = I_;
    srcs[5] = W_hh + ((size_t)(u * 3 + 0) * H_ + h0) * H_;   rstr[5] = H_;
    srcs[6] = W_hh + ((size_t)(u * 3 + 1) * H_ + h0) * H_;   rstr[6] = H_;
    srcs[7] = W_hh + ((size_t)(u * 3 + 2) * H_ + h0) * H_;   rstr[7] = H_;

    // Staging: thread covers row = tid/8, 4-float chunk c4 = (tid%8)*4
    const int srow = tid >> 3;        // 0..63
    const int c4   = (tid & 7) * 4;   // 0..28
    const float* tb[8];
    #pragma unroll
    for (int s = 0; s < 8; ++s) tb[s] = srcs[s] + (size_t)srow * rstr[s] + c4;

    floatx4 acc[3][2][2];
    #pragma unroll
    for (int g = 0; g < 3; ++g)
        #pragma unroll
        for (int mt = 0; mt < 2; ++mt)
            #pragma unroll
            for (int nt = 0; nt < 2; ++nt)
                acc[g][mt][nt] = (floatx4){0.f, 0.f, 0.f, 0.f};

    const int aslab = g2;            // A operand: X or Hprev
    const int bbase = 2 + 3 * g2;    // B operands: W_ih or W_hh slabs

    // ---- prologue: prefetch k=0 tile ----
    float4 pre[8];
    #pragma unroll
    for (int s = 0; s < 8; ++s) pre[s] = *(const float4*)(tb[s]);

    for (int k0 = 0; k0 < KDIM; k0 += BK) {
        // convert + write staged tile to LDS
        #pragma unroll
        for (int s = 0; s < 8; ++s) {
            uint2 w;
            w.x = pk2bf(pre[s].x, pre[s].y);
            w.y = pk2bf(pre[s].z, pre[s].w);
            *(uint2*)&smem.bf[s][srow * LSTR + c4] = w;
        }
        __syncthreads();

        // issue next tile's loads (overlap with MFMA below)
        if (k0 + BK < KDIM) {
            #pragma unroll
            for (int s = 0; s < 8; ++s) pre[s] = *(const float4*)(tb[s] + k0 + BK);
        }

        // MFMA: this wave-group's A slab x its 3 gate W slabs
        short8 afr[2];
        #pragma unroll
        for (int mt = 0; mt < 2; ++mt)
            afr[mt] = *(const short8*)&smem.bf[aslab][(wm * 32 + mt * 16 + lr) * LSTR + q * 8];
        #pragma unroll
        for (int g = 0; g < 3; ++g) {
            const short8 bf0 = *(const short8*)&smem.bf[bbase + g][(wn * 32 + lr) * LSTR + q * 8];
            const short8 bf1 = *(const short8*)&smem.bf[bbase + g][(wn * 32 + 16 + lr) * LSTR + q * 8];
            #pragma unroll
            for (int mt = 0; mt < 2; ++mt) {
                acc[g][mt][0] = __builtin_amdgcn_mfma_f32_16x16x32_bf16(afr[mt], bf0, acc[g][mt][0], 0, 0, 0);
                acc[g][mt][1] = __builtin_amdgcn_mfma_f32_16x16x32_bf16(afr[mt], bf1, acc[g][mt][1], 0, 0, 0);
            }
        }
        __syncthreads();
    }

    // ---- epilogue ----
    const float* bih = b_ih + u * (3 * H_);
    const float* bhh = b_hh + u * (3 * H_);

    if (g2 == 1) {
        // gh waves: add b_hh, publish to LDS
        #pragma unroll
        for (int nt = 0; nt < 2; ++nt) {
            const int col = wn * 32 + nt * 16 + lr;
            const float bhr = bhh[h0 + col];
            const float bhz = bhh[H_ + h0 + col];
            const float bhn = bhh[2 * H_ + h0 + col];
            #pragma unroll
            for (int mt = 0; mt < 2; ++mt) {
                #pragma unroll
                for (int r = 0; r < 4; ++r) {
                    const int row = wm * 32 + mt * 16 + q * 4 + r;
                    smem.ep[0][row * ESTR + col] = acc[0][mt][nt][r] + bhr;
                    smem.ep[1][row * ESTR + col] = acc[1][mt][nt][r] + bhz;
                    smem.ep[2][row * ESTR + col] = acc[2][mt][nt][r] + bhn;
                }
            }
        }
    }
    __syncthreads();

    if (g2 == 0) {
        // gx waves: combine, gate math, store
        #pragma unroll
        for (int nt = 0; nt < 2; ++nt) {
            const int col  = wn * 32 + nt * 16 + lr;
            const int hcol = h0 + col;
            const float bir  = bih[hcol];
            const float biz  = bih[H_ + hcol];
            const float bin_ = bih[2 * H_ + hcol];
            #pragma unroll
            for (int mt = 0; mt < 2; ++mt) {
                #pragma unroll
                for (int r = 0; r < 4; ++r) {
                    const int row  = wm * 32 + mt * 16 + q * 4 + r;
                    const int brow = b0 + row;
                    const size_t gidx = ((size_t)brow * U_ + u) * H_ + hcol;
                    const float hprev = hidden[gidx];
                    const float hr = smem.ep[0][row * ESTR + col];
                    const float hz = smem.ep[1][row * ESTR + col];
                    const float hn = smem.ep[2][row * ESTR + col];
                    const float xr = acc[0][mt][nt][r] + bir;
                    const float xz = acc[1][mt][nt][r] + biz;
                    const float xn = acc[2][mt][nt][r] + bin_;
                    const float rg = 1.f / (1.f + __expf(-(xr + hr)));
                    const float zg = 1.f / (1.f + __expf(-(xz + hz)));
                    const float ng = tanhf(xn + rg * hn);
                    out[gidx] = (1.f - zg) * ng + zg * hprev;
                }
            }
        }
    }
}

extern "C" void kernel_launch(void* const* d_in, const int* in_sizes, int n_in,
                              void* d_out, int out_size, void* d_ws, size_t ws_size,
                              hipStream_t stream) {
    const float* inputs = (const float*)d_in[0];
    const float* hidden = (const float*)d_in[1];
    const float* W_ih   = (const float*)d_in[2];
    const float* W_hh   = (const float*)d_in[3];
    const float* b_ih   = (const float*)d_in[4];
    const float* b_hh   = (const float*)d_in[5];
    float* out = (float*)d_out;

    dim3 grid(H_ / BN, B_ / BM, U_);  // (8, 16, 8) = 1024 blocks
    dim3 block(512);
    gru_fused_kernel<<<grid, block, 0, stream>>>(inputs, hidden, W_ih, W_hh,
                                                 b_ih, b_hh, out);
}